// Round 9
// baseline (196.085 us; speedup 1.0000x reference)
//
#include <hip/hip_runtime.h>
#include <hip/hip_bf16.h>

// ShapeAwareRoIAlign: mask-weighted RoIAlign.
//   features: [N=2, C=256, H=200, W=200] f32 (NCHW, 164 MB)
//   rois:     [R=512, 5] f32  (b, x1, y1, x2, y2) inclusive image coords
//   masks:    [R, MH=128, MW=128] f32
//   out:      [R, C, 7, 7] f32
//
// Round 15 (= round 14 resubmitted: round-14 bench died on GPU acquisition
// timeout, kernel untested).
// Harness model (residual accounting r0-r7): ~110 us/iter of fillBuffer
// restore is UNCONDITIONAL -- identical residual whether d_ws is touched or
// not. Therefore ws use is FREE. Total = ~110 + kernels.
// r7 main kernel = 69 us, VALUBusy 61% (~42 us VALU-issue): cvt_pk staging
// fix was NEUTRAL -> staging conversion was not the cost. Revised accounting:
// per-roi geometry (sample coords + mask bilinear + corner/weight folding,
// ~150 VALU x 3.1 waves) is recomputed 32x per roi = ~15-20 us GPU-wide.
// This round: (1) hoist geometry to a tiny precompute kernel -> 2.4 MB geo
// table in ws (free); main kernel stages it with one coalesced 8B+16B read.
// (2) XCD-chunked block swizzle so a roi's 32 blocks land on ONE XCD ->
// region L2-resident for 31/32 blocks instead of spread over 8 L2s.

constexpr int   OUT_H = 7, OUT_W = 7;
constexpr int   NBIN  = OUT_H * OUT_W;     // 49
constexpr float SCALE = 0.25f;
constexpr int   S     = 2;
constexpr int   NSAMP = NBIN * S * S;      // 196 sample points per roi
constexpr int   CG    = 8;                 // channels per block
constexpr int   NPAIR = CG / 2;            // 4 channel pairs
constexpr int   RDIM  = 34;                // max region rows
constexpr int   RCOLS = 40;                // padded region cols (10 float4)
constexpr int   PSTRIDE = RDIM * RCOLS * 2 + 4;  // u16 units per pair region (2724):
                                           // 8B-aligned; 1362 dwords mod 32 = 18
                                           // -> pair bases on distinct banks

typedef unsigned short ushort_t;

__device__ __forceinline__ unsigned pack_bf16_pair(float e, float o) {
    // low 16 = even channel, high 16 = odd channel; RNE via v_cvt_pk_bf16_f32
    __hip_bfloat162 h2 = __float22bfloat162_rn(make_float2(e, o));
    unsigned u;
    __builtin_memcpy(&u, &h2, sizeof(u));
    return u;
}

// Region bounds shared by both kernels (must match exactly).
__device__ __forceinline__ void region_bounds(float roi_start_h, float roi_start_w,
                                              float roi_h, float roi_w, int H, int W,
                                              int& y_lo, int& x_lo4, int& rows, int& cols4) {
    int yl = (int)floorf(roi_start_h); yl = max(0, min(yl, H - 1));
    int xl = (int)floorf(roi_start_w); xl = max(0, min(xl, W - 1));
    const int y_hi = max(yl, min((int)floorf(roi_start_h + roi_h) + 1, H - 1));
    const int x_hi = max(xl, min((int)floorf(roi_start_w + roi_w) + 1, W - 1));
    y_lo  = yl;
    rows  = min(y_hi - yl + 1, RDIM);
    x_lo4 = xl & ~3;                                  // 16B-aligned origin
    cols4 = min((x_hi - x_lo4 + 4) >> 2, RCOLS / 4);
    // x_lo4+4k (k<cols4) is a multiple of 4, <= x_hi <= W-1 -> <= W-4 when
    // W%4==0 (gated at launch): every float4 read in-bounds and 16B-aligned.
}

// ---------------------------------------------------------------------------
// Kernel 1: per-roi geometry precompute. Grid (R), 256 threads (196 active).
// Writes region-LOCAL byte offsets (ushort4) + folded weights
// (bilinear * mask * valid * 0.25, float4) to the ws geo table.
// ---------------------------------------------------------------------------
__global__ __launch_bounds__(256)
void geo_precompute_kernel(const float* __restrict__ rois,
                           const float* __restrict__ masks,
                           ushort4* __restrict__ gidx,
                           float4*  __restrict__ gw,
                           int H, int W, int MH, int MW) {
    const int r   = blockIdx.x;
    const int tid = threadIdx.x;
    if (tid >= NSAMP) return;

    const float* roi = rois + (size_t)r * 5;
    const float x1 = roi[1], y1 = roi[2], x2 = roi[3], y2 = roi[4];

    const float roi_start_w = x1 * SCALE;
    const float roi_start_h = y1 * SCALE;
    const float roi_w = fmaxf((x2 - x1 + 1.0f) * SCALE, 1.0f);
    const float roi_h = fmaxf((y2 - y1 + 1.0f) * SCALE, 1.0f);
    const float bin_w = roi_w * (1.0f / OUT_W);
    const float bin_h = roi_h * (1.0f / OUT_H);

    int y_lo, x_lo4, rows, cols4;
    region_bounds(roi_start_h, roi_start_w, roi_h, roi_w, H, W, y_lo, x_lo4, rows, cols4);

    const int bin = tid >> 2;          // 0..48
    const int sub = tid & 3;           // 0..3
    const int ph  = bin / OUT_W, pw = bin % OUT_W;
    const int iy  = sub >> 1,   ix = sub & 1;

    const float yy = roi_start_h + ((float)ph + ((float)iy + 0.5f) * (1.0f / S)) * bin_h;
    const float xx = roi_start_w + ((float)pw + ((float)ix + 0.5f) * (1.0f / S)) * bin_w;

    const bool valid = (yy > -1.0f) && (yy < (float)H) && (xx > -1.0f) && (xx < (float)W);

    // mask weight (roi-relative image coords)
    const float* msk = masks + (size_t)r * MH * MW;
    float my = fminf(fmaxf(yy * (1.0f / SCALE) - y1, 0.0f), y2 - y1);
    float mx = fminf(fmaxf(xx * (1.0f / SCALE) - x1, 0.0f), x2 - x1);
    my = fminf(fmaxf(my, 0.0f), (float)(MH - 1));
    mx = fminf(fmaxf(mx, 0.0f), (float)(MW - 1));
    const int my0 = (int)floorf(my), mx0 = (int)floorf(mx);
    const int my1 = min(my0 + 1, MH - 1), mx1 = min(mx0 + 1, MW - 1);
    const float mly = my - (float)my0, mlx = mx - (float)mx0;
    const float mhy = 1.0f - mly,      mhx = 1.0f - mlx;
    const float wgt = mhy * mhx * msk[my0 * MW + mx0] + mhy * mlx * msk[my0 * MW + mx1]
                    + mly * mhx * msk[my1 * MW + mx0] + mly * mlx * msk[my1 * MW + mx1];

    // feature corners -> region-local byte offsets + folded weights
    const float yc = fminf(fmaxf(yy, 0.0f), (float)(H - 1));
    const float xc = fminf(fmaxf(xx, 0.0f), (float)(W - 1));
    const int y0  = (int)floorf(yc), x0 = (int)floorf(xc);
    const int y1i = min(y0 + 1, H - 1), x1i = min(x0 + 1, W - 1);
    const float ly = yc - (float)y0, lx = xc - (float)x0;
    const float hy = 1.0f - ly,      hx = 1.0f - lx;

    const int ly0 = min(max(y0  - y_lo,  0), RDIM  - 1);
    const int ly1 = min(max(y1i - y_lo,  0), RDIM  - 1);
    const int lx0 = min(max(x0  - x_lo4, 0), RCOLS - 1);
    const int lx1 = min(max(x1i - x_lo4, 0), RCOLS - 1);

    const float scale_all = (valid ? wgt : 0.0f) * (1.0f / (float)(S * S));
    ushort4 o;                                    // byte offsets = dword_pix*4
    o.x = (ushort_t)((ly0 * RCOLS + lx0) * 4);
    o.y = (ushort_t)((ly0 * RCOLS + lx1) * 4);
    o.z = (ushort_t)((ly1 * RCOLS + lx0) * 4);
    o.w = (ushort_t)((ly1 * RCOLS + lx1) * 4);
    float4 w4;
    w4.x = hy * hx * scale_all;
    w4.y = hy * lx * scale_all;
    w4.z = ly * hx * scale_all;
    w4.w = ly * lx * scale_all;
    gidx[(size_t)r * NSAMP + tid] = o;
    gw  [(size_t)r * NSAMP + tid] = w4;
}

// ---------------------------------------------------------------------------
// Kernel 2: gather. 1D grid (R * C/8), 256 threads, XCD-chunked swizzle.
//   A: threads 0..195 read geo table (coalesced 8B + 16B) -> s_idx/s_w.
//   B: stage region [pair][px][2ch] bf16 (float4 reads, cvt_pk, b64 writes).
//   D: gather: thread = (pair, bin); per corner one ds_read_b32 = 2 channels.
//   E: results via LDS (reuse region buffer), coalesced out.
// ---------------------------------------------------------------------------
__global__ __launch_bounds__(256, 6)
void roialign_gather_kernel(const float* __restrict__ features,
                            const float* __restrict__ rois,
                            const ushort4* __restrict__ gidx,
                            const float4*  __restrict__ gw,
                            float*       __restrict__ out,
                            int C, int H, int W, int n_cg, int swz) {
    __shared__ __align__(16) ushort_t s_reg[NPAIR * PSTRIDE];  // 21,792 B
    __shared__ ushort4 s_idx[NSAMP];                           //  1,568 B
    __shared__ float4  s_w[NSAMP];                             //  3,136 B

    // XCD-chunked swizzle: consecutive hardware dispatch ids round-robin over
    // 8 XCDs; map so each roi's n_cg blocks share one XCD (L2 locality).
    int gid = blockIdx.x;
    if (swz) {
        const int per_xcd = (int)gridDim.x >> 3;
        gid = (gid & 7) * per_xcd + (gid >> 3);
    }
    const int r   = gid / n_cg;
    const int cgp = gid - r * n_cg;
    const int tid = threadIdx.x;

    const float* roi = rois + (size_t)r * 5;
    const int   b  = (int)roi[0];
    const float x1 = roi[1], y1 = roi[2], x2 = roi[3], y2 = roi[4];

    const float roi_start_w = x1 * SCALE;
    const float roi_start_h = y1 * SCALE;
    const float roi_w = fmaxf((x2 - x1 + 1.0f) * SCALE, 1.0f);
    const float roi_h = fmaxf((y2 - y1 + 1.0f) * SCALE, 1.0f);

    int y_lo, x_lo4, rows, cols4;
    region_bounds(roi_start_h, roi_start_w, roi_h, roi_w, H, W, y_lo, x_lo4, rows, cols4);

    // ---- phase A: stage geo table (coalesced) ----
    if (tid < NSAMP) {
        s_idx[tid] = gidx[(size_t)r * NSAMP + tid];
        s_w[tid]   = gw  [(size_t)r * NSAMP + tid];
    }

    // ---- phase B: stage feature region (packed channel pairs) ----
    {
        const int g    = tid >> 5;        // 0..7
        const int lane = tid & 31;
        const int pr   = g >> 1;          // pair 0..3
        const int part = g & 1;           // phase half
        const size_t HWs = (size_t)H * W;
        const float* srcE = features + ((size_t)b * C + (size_t)(cgp * CG + 2 * pr)) * HWs
                          + (size_t)y_lo * W + x_lo4;
        const float* srcO = srcE + HWs;
        unsigned* dp32base = (unsigned*)(s_reg + pr * PSTRIDE);
        const int items = rows * cols4;
        const float rcp = 1.0f / (float)cols4;
#pragma unroll 2
        for (int it = lane + part * 32; it < items; it += 64) {
            int ry = (int)((float)it * rcp);
            int k  = it - ry * cols4;
            if (k >= cols4) { ry++; k -= cols4; }
            if (k < 0)      { ry--; k += cols4; }
            const float4 vE = *(const float4*)(srcE + ry * W + 4 * k);
            const float4 vO = *(const float4*)(srcO + ry * W + 4 * k);
            const int pix = ry * RCOLS + 4 * k;              // dword index
            uint2 a, c2;
            a.x  = pack_bf16_pair(vE.x, vO.x);
            a.y  = pack_bf16_pair(vE.y, vO.y);
            c2.x = pack_bf16_pair(vE.z, vO.z);
            c2.y = pack_bf16_pair(vE.w, vO.w);
            *(uint2*)(dp32base + pix)     = a;               // 8B, 8B-aligned
            *(uint2*)(dp32base + pix + 2) = c2;
        }
    }
    __syncthreads();

    // ---- phase D: gather: thread = (pair, bin); 2 channels per thread ----
    float accE = 0.0f, accO = 0.0f;
    const int pr  = tid & 3;
    const int bin = tid >> 2;
    if (tid < NSAMP) {                                 // 196 = 4 pairs x 49 bins
        const char* base = (const char*)s_reg + pr * (PSTRIDE * 2);
#pragma unroll
        for (int sub = 0; sub < 4; ++sub) {
            const int s = bin * 4 + sub;
            const ushort4 off = s_idx[s];              // broadcast across 4 pr lanes
            const float4  w   = s_w[s];
            const unsigned q0 = *(const unsigned*)(base + off.x);
            const unsigned q1 = *(const unsigned*)(base + off.y);
            const unsigned q2 = *(const unsigned*)(base + off.z);
            const unsigned q3 = *(const unsigned*)(base + off.w);
            accE = fmaf(w.x, __uint_as_float(q0 << 16),          accE);
            accO = fmaf(w.x, __uint_as_float(q0 & 0xffff0000u),  accO);
            accE = fmaf(w.y, __uint_as_float(q1 << 16),          accE);
            accO = fmaf(w.y, __uint_as_float(q1 & 0xffff0000u),  accO);
            accE = fmaf(w.z, __uint_as_float(q2 << 16),          accE);
            accO = fmaf(w.z, __uint_as_float(q2 & 0xffff0000u),  accO);
            accE = fmaf(w.w, __uint_as_float(q3 << 16),          accE);
            accO = fmaf(w.w, __uint_as_float(q3 & 0xffff0000u),  accO);
        }
    }
    __syncthreads();   // region reads done before LDS reuse

    // ---- phase E: stage results (reuse region LDS), coalesced write ----
    float* s_out = (float*)s_reg;               // 8*49 f32 = 1.57 KB
    if (tid < NSAMP) {
        s_out[(2 * pr + 0) * NBIN + bin] = accE;
        s_out[(2 * pr + 1) * NBIN + bin] = accO;
    }
    __syncthreads();

    float* outr = out + ((size_t)r * C + (size_t)cgp * CG) * NBIN;
    for (int i = tid; i < CG * NBIN; i += 256)
        outr[i] = s_out[i];
}

// ---------------------------------------------------------------------------
// Fallback for unexpected shapes / tiny ws. No workspace.
// ---------------------------------------------------------------------------
__global__ __launch_bounds__(256)
void mask_roialign_kernel(const float* __restrict__ features,
                          const float* __restrict__ rois,
                          const float* __restrict__ masks,
                          float*       __restrict__ out,
                          int C, int H, int W, int MH, int MW) {
    int blk = blockIdx.x;
    int pw  = blk % OUT_W;
    int ph  = (blk / OUT_W) % OUT_H;
    int r   = blk / (OUT_W * OUT_H);
    int c   = threadIdx.x;
    if (c >= C) return;

    const float* roi = rois + (size_t)r * 5;
    int   b  = (int)roi[0];
    float x1 = roi[1], y1 = roi[2], x2 = roi[3], y2 = roi[4];

    float roi_start_w = x1 * SCALE;
    float roi_start_h = y1 * SCALE;
    float roi_w = fmaxf((x2 - x1 + 1.0f) * SCALE, 1.0f);
    float roi_h = fmaxf((y2 - y1 + 1.0f) * SCALE, 1.0f);
    float bin_w = roi_w / (float)OUT_W;
    float bin_h = roi_h / (float)OUT_H;

    const float* fch = features + ((size_t)b * C + c) * (size_t)(H * W);
    const float* msk = masks + (size_t)r * MH * MW;

    float acc = 0.0f;
#pragma unroll
    for (int iy = 0; iy < S; ++iy) {
        float yy = roi_start_h + ((float)ph + ((float)iy + 0.5f) / (float)S) * bin_h;
#pragma unroll
        for (int ix = 0; ix < S; ++ix) {
            float xx = roi_start_w + ((float)pw + ((float)ix + 0.5f) / (float)S) * bin_w;
            bool valid = (yy > -1.0f) && (yy < (float)H) && (xx > -1.0f) && (xx < (float)W);
            float my = fminf(fmaxf(yy / SCALE - y1, 0.0f), fminf(y2 - y1, (float)(MH - 1)));
            float mx = fminf(fmaxf(xx / SCALE - x1, 0.0f), fminf(x2 - x1, (float)(MW - 1)));
            int my0 = (int)floorf(my), mx0 = (int)floorf(mx);
            int my1 = min(my0 + 1, MH - 1), mx1 = min(mx0 + 1, MW - 1);
            float mly = my - my0, mlx = mx - mx0, mhy = 1.0f - mly, mhx = 1.0f - mlx;
            float wgt = mhy * mhx * msk[my0 * MW + mx0] + mhy * mlx * msk[my0 * MW + mx1]
                      + mly * mhx * msk[my1 * MW + mx0] + mly * mlx * msk[my1 * MW + mx1];
            if (valid) {
                float yc = fminf(fmaxf(yy, 0.0f), (float)(H - 1));
                float xc = fminf(fmaxf(xx, 0.0f), (float)(W - 1));
                int y0 = (int)floorf(yc), x0 = (int)floorf(xc);
                int y1i = min(y0 + 1, H - 1), x1i = min(x0 + 1, W - 1);
                float ly = yc - y0, lx = xc - x0, hy = 1.0f - ly, hx = 1.0f - lx;
                float v = hy * hx * fch[y0  * W + x0 ] + hy * lx * fch[y0  * W + x1i]
                        + ly * hx * fch[y1i * W + x0 ] + ly * lx * fch[y1i * W + x1i];
                acc += wgt * v;
            }
        }
    }
    out[((size_t)r * C + c) * (size_t)NBIN + ph * OUT_W + pw] = acc * (1.0f / (S * S));
}

extern "C" void kernel_launch(void* const* d_in, const int* in_sizes, int n_in,
                              void* d_out, int out_size, void* d_ws, size_t ws_size,
                              hipStream_t stream) {
    const float* features = (const float*)d_in[0];
    const float* rois     = (const float*)d_in[1];
    const float* masks    = (const float*)d_in[2];
    float*       out      = (float*)d_out;

    const int R  = in_sizes[1] / 5;                       // 512
    const int C  = out_size / (R * NBIN);                 // 256
    const int H  = 200, W = 200;                          // fixed by reference
    const int MH = 128, MW = 128;                         // fixed by reference

    const size_t gidx_bytes = (size_t)R * NSAMP * sizeof(ushort4);  // 0.8 MB
    const size_t gw_bytes   = (size_t)R * NSAMP * sizeof(float4);   // 1.6 MB

    if ((C % CG == 0) && (W % 4 == 0) && ws_size >= gidx_bytes + gw_bytes) {
        ushort4* gidx = (ushort4*)d_ws;
        float4*  gw   = (float4*)((char*)d_ws + gidx_bytes);   // 16B-aligned
        const int n_cg = C / CG;                               // 32
        const int nblk = R * n_cg;                             // 16384
        const int swz  = (nblk % 8 == 0) ? 1 : 0;

        geo_precompute_kernel<<<dim3(R), dim3(256), 0, stream>>>(
            rois, masks, gidx, gw, H, W, MH, MW);
        roialign_gather_kernel<<<dim3(nblk), dim3(256), 0, stream>>>(
            features, rois, gidx, gw, out, C, H, W, n_cg, swz);
    } else {
        mask_roialign_kernel<<<dim3(R * NBIN), dim3(256), 0, stream>>>(
            features, rois, masks, out, C, H, W, MH, MW);
    }
}